// Round 3
// baseline (41.089 us; speedup 1.0000x reference)
//
#include <hip/hip_runtime.h>
#include <math.h>

#define NB       16
#define IMG      127
#define PLANE    (IMG * IMG)            // 16129
#define INC      64
#define PN       4096
#define NTHREADS 512
#define PPT      8                      // consecutive output rows per thread

#define GLOBAL_AS __attribute__((address_space(1)))
#define LDS_AS    __attribute__((address_space(3)))

// index into upper-triangular symmetric 9x9 storage, requires p<=q
__device__ __forceinline__ constexpr int symidx(int p, int q) {
    return p * 9 - (p * (p - 1)) / 2 + (q - p);
}

// full 64-lane sum via DPP adds (VALU pipe only); result valid in lane 63
__device__ __forceinline__ float wave_reduce_sum(float v) {
#define DPP_ADD(ctrl)                                                          \
    v += __builtin_bit_cast(float, __builtin_amdgcn_update_dpp(                \
             0, __builtin_bit_cast(int, v), (ctrl), 0xf, 0xf, true))
    DPP_ADD(0x111);   // row_shr:1
    DPP_ADD(0x112);   // row_shr:2
    DPP_ADD(0x114);   // row_shr:4
    DPP_ADD(0x118);   // row_shr:8
    DPP_ADD(0x142);   // row_bcast:15
    DPP_ADD(0x143);   // row_bcast:31 -> lane63 = sum(0..63)
#undef DPP_ADD
    return v;
}

// load one patch row's 3 taps with bounds handling (rok scalar, c0/c2 per-lane)
#define LOAD_ROW(d0, d1, d2, ihv)                                              \
    {                                                                          \
        const int  ih_ = (ihv);                                                \
        const bool rok = (unsigned)ih_ < (unsigned)IMG;                        \
        const int  ba  = ih_ * IMG + iw0;                                      \
        d0 = (rok && c0) ? plane[ba]     : 0.f;                                \
        d1 =  rok        ? plane[ba + 1] : 0.f;                                \
        d2 = (rok && c2) ? plane[ba + 2] : 0.f;                                \
    }

__global__ void __launch_bounds__(NTHREADS, 4)
scann_fused(const float* __restrict__ x,
            const float* __restrict__ Wq, const float* __restrict__ bq,
            const float* __restrict__ Wk, const float* __restrict__ bk,
            const float* __restrict__ Wv, const float* __restrict__ bv,
            const float* __restrict__ Wo, const float* __restrict__ bo,
            float* __restrict__ out)
{
    __shared__ float plane[PLANE];              // 64516 B: whole channel plane
    __shared__ float red[8 * 54];               // per-wave partials (45 Gram + 9 sums)
    __shared__ float Msh[45];                   // Gram (upper tri)
    __shared__ float msh[9];                    // column sums
    __shared__ float MW[81];                    // M @ Wq
    __shared__ float Wq_s[81], Wk_s[81], Wv_s[81];
    __shared__ float bq_s[9], bk_s[9], bv_s[9], Wo_s[9];
    __shared__ float en[81], at[81], wt[9], u_s[9];
    __shared__ float c_s, bo_sh;

    const int bg  = blockIdx.x;                 // b*64 + g
    const int g   = bg & 63;
    const int tid = threadIdx.x;
    const int ow  = tid & 63;                   // lane = output col
    const int wv  = tid >> 6;                   // wave id 0..7
    const int oh0 = wv * PPT;                   // first output row of this thread

    const float* __restrict__ xp = x + (size_t)bg * PLANE;

    // ---- stage plane: peel to 16B alignment, 7 x width-16 async rounds, tail ----
    const int a0 = (4 - (bg & 3)) & 3;          // head floats to reach 16B alignment
    if (tid < a0) plane[tid] = xp[tid];
    #pragma unroll
    for (int j = 0; j < 7; ++j) {
        __builtin_amdgcn_global_load_lds(
            (const GLOBAL_AS void*)(xp + a0 + (j * NTHREADS + tid) * 4),
            (LDS_AS void*)(&plane[a0 + (j * NTHREADS + wv * 64) * 4]), 16, 0, 0);
    }
    {
        const int base = a0 + 7 * NTHREADS * 4;         // a0 + 14336
        const int cnt  = PLANE - base;                  // 1790..1793
        for (int i = tid; i < cnt; i += NTHREADS)
            plane[base + i] = xp[base + i];
    }

    // stage tiny weights (disjoint thread ranges)
    if (tid < 81) {
        Wq_s[tid] = Wq[g * 81 + tid];
        Wk_s[tid] = Wk[g * 81 + tid];
        Wv_s[tid] = Wv[g * 81 + tid];
    } else if (tid >= 128 && tid < 137) {
        const int i = tid - 128;
        bq_s[i] = bq[g * 9 + i];
        bk_s[i] = bk[g * 9 + i];
        bv_s[i] = bv[g * 9 + i];
        Wo_s[i] = Wo[g * 9 + i];
    } else if (tid == 192) {
        bo_sh = bo[g];
    }
    __syncthreads();                            // barrier A

    const int  iw0 = ow * 2 - 1;
    const bool c0  = (ow > 0), c2 = (ow < 63);
    const int  ih0 = oh0 * 2 - 1;

    // ---- phase 1, pass A: Gram rows p=0..2 (24 entries) + column sums m (9) ----
    {
        float mA[24], mm[9], v[9];
        #pragma unroll
        for (int i = 0; i < 24; ++i) mA[i] = 0.f;
        #pragma unroll
        for (int i = 0; i < 9; ++i)  mm[i] = 0.f;
        LOAD_ROW(v[0], v[1], v[2], ih0 + 0);
        LOAD_ROW(v[3], v[4], v[5], ih0 + 1);
        LOAD_ROW(v[6], v[7], v[8], ih0 + 2);
        #pragma unroll
        for (int k = 0; k < PPT; ++k) {
            #pragma unroll
            for (int p = 0; p < 9; ++p) mm[p] += v[p];
            int idx = 0;
            #pragma unroll
            for (int p = 0; p < 3; ++p)
                #pragma unroll
                for (int q = p; q < 9; ++q)
                    mA[idx++] += v[p] * v[q];
            if (k < PPT - 1) {
                v[0] = v[6]; v[1] = v[7]; v[2] = v[8];
                LOAD_ROW(v[3], v[4], v[5], ih0 + 2 * (k + 1) + 1);
                LOAD_ROW(v[6], v[7], v[8], ih0 + 2 * (k + 1) + 2);
            }
        }
        #pragma unroll
        for (int i = 0; i < 24; ++i) mA[i] = wave_reduce_sum(mA[i]);
        #pragma unroll
        for (int i = 0; i < 9; ++i)  mm[i] = wave_reduce_sum(mm[i]);
        if (ow == 63) {
            #pragma unroll
            for (int i = 0; i < 24; ++i) red[wv * 54 + i]      = mA[i];
            #pragma unroll
            for (int i = 0; i < 9; ++i)  red[wv * 54 + 45 + i] = mm[i];
        }
    }

    // ---- phase 1, pass B: Gram rows p=3..8 (21 entries) ----
    {
        float mB[21], v[9];
        #pragma unroll
        for (int i = 0; i < 21; ++i) mB[i] = 0.f;
        LOAD_ROW(v[0], v[1], v[2], ih0 + 0);
        LOAD_ROW(v[3], v[4], v[5], ih0 + 1);
        LOAD_ROW(v[6], v[7], v[8], ih0 + 2);
        #pragma unroll
        for (int k = 0; k < PPT; ++k) {
            int idx = 0;
            #pragma unroll
            for (int p = 3; p < 9; ++p)
                #pragma unroll
                for (int q = p; q < 9; ++q)
                    mB[idx++] += v[p] * v[q];
            if (k < PPT - 1) {
                v[0] = v[6]; v[1] = v[7]; v[2] = v[8];
                LOAD_ROW(v[3], v[4], v[5], ih0 + 2 * (k + 1) + 1);
                LOAD_ROW(v[6], v[7], v[8], ih0 + 2 * (k + 1) + 2);
            }
        }
        #pragma unroll
        for (int i = 0; i < 21; ++i) mB[i] = wave_reduce_sum(mB[i]);
        if (ow == 63) {
            #pragma unroll
            for (int i = 0; i < 21; ++i) red[wv * 54 + 24 + i] = mB[i];
        }
    }
    __syncthreads();                            // barrier B

    // ---- tiny math, all inside wave 0 (in-wave LDS program order) ----
    if (wv == 0) {
        const int lane = ow;
        if (lane < 54) {                        // cross-wave final reduce
            float s = 0.f;
            #pragma unroll
            for (int w = 0; w < 8; ++w) s += red[w * 54 + lane];
            if (lane < 45) Msh[lane]      = s;
            else           msh[lane - 45] = s;
        }
        #pragma unroll
        for (int r = 0; r < 2; ++r) {           // MW = M @ Wq (81 entries)
            const int e = lane + r * 64;
            if (e < 81) {
                const int p = e / 9, t = e % 9;
                float acc = 0.f;
                #pragma unroll
                for (int q = 0; q < 9; ++q) {
                    const int a_ = p < q ? p : q, b_ = p < q ? q : p;
                    acc += Msh[symidx(a_, b_)] * Wq_s[q * 9 + t];
                }
                MW[e] = acc;
            }
        }
        #pragma unroll
        for (int r = 0; r < 2; ++r) {           // energy
            const int e = lane + r * 64;
            if (e < 81) {
                const int s = e / 9, t = e % 9;
                float km = 0.f, qm = 0.f, acc = 0.f;
                #pragma unroll
                for (int p = 0; p < 9; ++p) {
                    km  += Wk_s[p * 9 + s] * msh[p];
                    qm  += Wq_s[p * 9 + t] * msh[p];
                    acc += Wk_s[p * 9 + s] * MW[p * 9 + t];
                }
                en[e] = acc + (float)PN * bk_s[s] * bq_s[t] + km * bq_s[t] + bk_s[s] * qm;
            }
        }
        if (lane < 9) {                         // softmax over t per row s
            const int s = lane;
            float mx = en[s * 9];
            #pragma unroll
            for (int t = 1; t < 9; ++t) mx = fmaxf(mx, en[s * 9 + t]);
            float ex[9], sum = 0.f;
            #pragma unroll
            for (int t = 0; t < 9; ++t) { ex[t] = expf(en[s * 9 + t] - mx); sum += ex[t]; }
            const float inv = 1.f / sum;
            #pragma unroll
            for (int t = 0; t < 9; ++t) at[s * 9 + t] = ex[t] * inv;
        }
        if (lane < 9) {                         // wt[t] = sum_s attn[s,t] * Wo[s]
            const int t = lane;
            float w = 0.f;
            #pragma unroll
            for (int s = 0; s < 9; ++s) w += at[s * 9 + t] * Wo_s[s];
            wt[t] = w;
        }
        if (lane < 9) {                         // u[p] = sum_t Wv[p,t] * wt[t]
            const int p = lane;
            float uu = 0.f;
            #pragma unroll
            for (int t = 0; t < 9; ++t) uu += Wv_s[p * 9 + t] * wt[t];
            u_s[p] = uu;
        }
        if (lane == 12) {                       // c = bv.wt + bo
            float cc = bo_sh;
            #pragma unroll
            for (int t = 0; t < 9; ++t) cc += bv_s[t] * wt[t];
            c_s = cc;
        }
    }
    __syncthreads();                            // barrier E

    // ---- phase 2: out[l] = t_l . u + c ----
    float ur[9];
    #pragma unroll
    for (int i = 0; i < 9; ++i) ur[i] = u_s[i];
    const float cc = c_s;
    float* __restrict__ op = out + (size_t)bg * PN;

    {
        float v[9];
        LOAD_ROW(v[0], v[1], v[2], ih0 + 0);
        LOAD_ROW(v[3], v[4], v[5], ih0 + 1);
        LOAD_ROW(v[6], v[7], v[8], ih0 + 2);
        #pragma unroll
        for (int k = 0; k < PPT; ++k) {
            float o = cc;
            #pragma unroll
            for (int i = 0; i < 9; ++i) o += v[i] * ur[i];
            op[(oh0 + k) * 64 + ow] = o;
            if (k < PPT - 1) {
                v[0] = v[6]; v[1] = v[7]; v[2] = v[8];
                LOAD_ROW(v[3], v[4], v[5], ih0 + 2 * (k + 1) + 1);
                LOAD_ROW(v[6], v[7], v[8], ih0 + 2 * (k + 1) + 2);
            }
        }
    }
}

extern "C" void kernel_launch(void* const* d_in, const int* in_sizes, int n_in,
                              void* d_out, int out_size, void* d_ws, size_t ws_size,
                              hipStream_t stream) {
    (void)in_sizes; (void)n_in; (void)d_ws; (void)ws_size; (void)out_size;
    const float* x  = (const float*)d_in[0];
    const float* Wq = (const float*)d_in[1];
    const float* bq = (const float*)d_in[2];
    const float* Wk = (const float*)d_in[3];
    const float* bk = (const float*)d_in[4];
    const float* Wv = (const float*)d_in[5];
    const float* bv = (const float*)d_in[6];
    const float* Wo = (const float*)d_in[7];
    const float* bo = (const float*)d_in[8];
    float* out = (float*)d_out;

    dim3 grid(NB * INC), block(NTHREADS);
    hipLaunchKernelGGL(scann_fused, grid, block, 0, stream,
                       x, Wq, bq, Wk, bk, Wv, bv, Wo, bo, out);
}